// Round 9
// baseline (75.527 us; speedup 1.0000x reference)
//
#include <hip/hip_runtime.h>
#include <math.h>

#define B_  2
#define N_  2048
#define NT_ 8
#define DZ_ 16
#define H_  64
#define W_  64

#define XGRID_SIZE (B_*NT_*H_*W_*3)   // 196608 floats
#define CUT 12.0f                     // keep if dt^2+di^2 < 12 (w > 2.4e-4)
#define CH  128                       // K-chunk: 4 waves x K=32

using half8   = __attribute__((ext_vector_type(8))) _Float16;
using floatx4 = __attribute__((ext_vector_type(4))) float;

// ---------------------------------------------------------------------------
// R9: hoist the t-cull out of the 1024-block loop.
//
// R8 analysis: phase 2 is ~1.6K cy/wave, but every block re-scanned all
// N=2048 points with stride-3 loads + ballot/atomic chains (O(N) cull around
// O(M) compute). Split:
//   kernel A (16 blocks, one per (b,t)): compact dt^2 < CUT survivors into
//     d_ws as float4 {x1*r1, x2*r2, dt^2, n_bits} + count. ~40% survive.
//   kernel B (1024 blocks): phase 1 scans only the pre-culled list with
//     coalesced float4 loads, 1 fma + cmp per entry; phases 2/3 = R8's
//     barrier-free k-split MFMA loop (f16 16x16x32, layouts verified).
// No atomics to global, no memset; ws = 516 KB.
// ---------------------------------------------------------------------------

__global__ __launch_bounds__(1024) void tcull_kernel(
    const float* __restrict__ x,      // [B][N][3]
    const float* __restrict__ tg,     // [B][NT]
    const float* __restrict__ lsp,    // [3]
    float4* __restrict__ wsl,         // [16][N_] packed survivors
    int* __restrict__ wcnt)           // [16] counts
{
    const int bt   = blockIdx.x;      // b*8 + t
    const int b    = bt >> 3;
    const int t    = bt & 7;
    const int tid  = threadIdx.x;
    const int lane = tid & 63;

    const float C = 0.84932180f;      // sqrt(0.5 * log2(e))
    const float r0 = C / (1e-5f + log1pf(expf(lsp[0])));
    const float r1 = C / (1e-5f + log1pf(expf(lsp[1])));
    const float r2 = C / (1e-5f + log1pf(expf(lsp[2])));

    const float tval = tg[b*NT_ + t];

    __shared__ int s_cnt;
    if (tid == 0) s_cnt = 0;
    __syncthreads();

    const float* __restrict__ xb = x + b*N_*3;
    float4* __restrict__ outl = wsl + (size_t)bt * N_;

    for (int k0 = 0; k0 < N_; k0 += 1024) {
        int k = k0 + tid;
        float x0 = xb[k*3 + 0];
        float x1 = xb[k*3 + 1];
        float x2 = xb[k*3 + 2];
        float dt  = (tval - x0) * r0;
        float dt2 = dt * dt;
        bool keep = (dt2 < CUT);
        unsigned long long mb = __ballot(keep);
        int cnt = __popcll(mb);
        int base = 0;
        if (lane == 0) base = atomicAdd(&s_cnt, cnt);
        base = __shfl(base, 0, 64);
        if (keep) {
            int rank = __popcll(mb & ((1ull << lane) - 1ull));
            outl[base + rank] =
                make_float4(x1 * r1, x2 * r2, dt2, __int_as_float(k));
        }
    }
    __syncthreads();
    if (tid == 0) wcnt[bt] = s_cnt;
}

__global__ __launch_bounds__(256, 4) void fused_kernel(
    const float* __restrict__ z,      // [B][N][16]
    const float* __restrict__ tg,     // [B][NT]
    const float* __restrict__ lsp,    // [3]
    const float4* __restrict__ wsl,   // [16][N_] pre-culled
    const int* __restrict__ wcnt,     // [16]
    float* __restrict__ out)          // x_grid (196608) ++ z_grid (1048576)
{
    const int i    = blockIdx.x & 63;
    const int t    = (blockIdx.x >> 6) & 7;
    const int b    = blockIdx.x >> 9;
    const int bt   = b*NT_ + t;
    const int tid  = threadIdx.x;
    const int w    = tid >> 6;        // wave id = k-subrange
    const int lane = tid & 63;
    const int quad = lane >> 4;       // 0..3
    const int col  = lane & 15;       // A row (j in tile) / B col (e)

    const float step = 2.0f / 63.0f;
    const float C    = 0.84932180f;

    const float r1 = C / (1e-5f + log1pf(expf(lsp[1])));
    const float r2 = C / (1e-5f + log1pf(expf(lsp[2])));

    const float tval = tg[bt];
    const float gi   = -1.0f + step * (float)i;
    const float gir1 = gi * r1;

    union REDU {
        float2 cuc[N_ + CH];           // {s, cx}: 17408 B (phases 1-2)
        float  red[4][64][DZ_ + 1];    // 17408 B (epilogue reduce)
    };
    __shared__ REDU sm;
    __shared__ int  cidx[N_ + CH];     // 8704 B
    __shared__ int  s_cnt, s_Mt;

    if (tid == 0) { s_cnt = 0; s_Mt = wcnt[bt]; }
    __syncthreads();
    const int Mt = s_Mt;

    // ---- phase 1: i-cull over the pre-culled (b,t) list ----
    const float4* __restrict__ lst = wsl + (size_t)bt * N_;
    for (int k0 = 0; k0 < Mt; k0 += 256) {
        int k = k0 + tid;
        bool keep = false;
        float sq = 0.f, cx = 0.f;
        int   n  = 0;
        if (k < Mt) {
            float4 f = lst[k];              // coalesced float4
            float di = gir1 - f.x;
            sq = fmaf(di, di, f.z);
            cx = f.y;
            n  = __float_as_int(f.w);
            keep = (sq < CUT);
        }
        unsigned long long mb = __ballot(keep);
        int cnt = __popcll(mb);
        int base = 0;
        if (lane == 0) base = atomicAdd(&s_cnt, cnt);
        base = __shfl(base, 0, 64);
        if (keep) {
            int rank = __popcll(mb & ((1ull << lane) - 1ull));
            int pos  = base + rank;
            sm.cuc[pos] = make_float2(sq, cx);
            cidx[pos]   = n;
        }
    }

    // x_grid row for this (b,t,i): 192 floats, coalesced
    if (tid < 192) {
        int jj = tid / 3;
        int c  = tid - jj*3;
        float gj = -1.0f + step * (float)jj;
        float v  = (c == 0) ? tval : ((c == 1) ? gi : gj);
        out[(size_t)blockIdx.x * 192 + tid] = v;
    }

    __syncthreads();
    const int M = s_cnt;
    if (tid < CH) {                    // pad: s huge -> exp2(-(d^2+s)) == 0
        sm.cuc[M + tid] = make_float2(1e9f, 0.f);
        cidx[M + tid]   = 0;
    }
    __syncthreads();

    const int NC = (M + CH - 1) / CH;  // 128-entry chunks

    // ---- phase 2: barrier-free MFMA K-loop (R8 structure) ----
    const float* __restrict__ zb = z + b*N_*DZ_;
    const int koff = w*32 + (quad << 3);   // this lane's k-base within a chunk

    const float aj0 = (-1.0f + step * (float)( 0 + col)) * r2;
    const float aj1 = (-1.0f + step * (float)(16 + col)) * r2;
    const float aj2 = (-1.0f + step * (float)(32 + col)) * r2;
    const float aj3 = (-1.0f + step * (float)(48 + col)) * r2;

    floatx4 acc0 = {0.f,0.f,0.f,0.f};
    floatx4 acc1 = {0.f,0.f,0.f,0.f};
    floatx4 acc2 = {0.f,0.f,0.f,0.f};
    floatx4 acc3 = {0.f,0.f,0.f,0.f};

    float zreg[8];
    {
        int idx[8];
        #pragma unroll
        for (int jj = 0; jj < 8; ++jj) idx[jj] = cidx[koff + jj];
        #pragma unroll
        for (int jj = 0; jj < 8; ++jj)
            zreg[jj] = zb[(size_t)idx[jj] * DZ_ + col];
    }

    for (int c = 0; c < NC; ++c) {
        half8 bf;
        #pragma unroll
        for (int jj = 0; jj < 8; ++jj) bf[jj] = (_Float16)zreg[jj];

        const int base = c*CH + koff;
        float2 mm[8];
        #pragma unroll
        for (int jj = 0; jj < 8; ++jj) mm[jj] = sm.cuc[base + jj];

        if (c + 1 < NC) {
            const int base2 = (c + 1)*CH + koff;
            int idx[8];
            #pragma unroll
            for (int jj = 0; jj < 8; ++jj) idx[jj] = cidx[base2 + jj];
            #pragma unroll
            for (int jj = 0; jj < 8; ++jj)
                zreg[jj] = zb[(size_t)idx[jj] * DZ_ + col];
        }

        half8 a0, a1, a2, a3;
        #pragma unroll
        for (int jj = 0; jj < 8; ++jj) {
            float s  = mm[jj].x;
            float cx = mm[jj].y;
            float d0 = aj0 - cx;
            float d1 = aj1 - cx;
            float d2 = aj2 - cx;
            float d3 = aj3 - cx;
            a0[jj] = (_Float16)exp2f(-fmaf(d0, d0, s));
            a1[jj] = (_Float16)exp2f(-fmaf(d1, d1, s));
            a2[jj] = (_Float16)exp2f(-fmaf(d2, d2, s));
            a3[jj] = (_Float16)exp2f(-fmaf(d3, d3, s));
        }

        acc0 = __builtin_amdgcn_mfma_f32_16x16x32_f16(a0, bf, acc0, 0, 0, 0);
        acc1 = __builtin_amdgcn_mfma_f32_16x16x32_f16(a1, bf, acc1, 0, 0, 0);
        acc2 = __builtin_amdgcn_mfma_f32_16x16x32_f16(a2, bf, acc2, 0, 0, 0);
        acc3 = __builtin_amdgcn_mfma_f32_16x16x32_f16(a3, bf, acc3, 0, 0, 0);
    }

    __syncthreads();   // all cuc reads done before red overlays it

    // ---- epilogue: reduce 4 k-partials across waves, store z_grid ----
    #pragma unroll
    for (int r = 0; r < 4; ++r) sm.red[w][ 0 + quad*4 + r][col] = acc0[r];
    #pragma unroll
    for (int r = 0; r < 4; ++r) sm.red[w][16 + quad*4 + r][col] = acc1[r];
    #pragma unroll
    for (int r = 0; r < 4; ++r) sm.red[w][32 + quad*4 + r][col] = acc2[r];
    #pragma unroll
    for (int r = 0; r < 4; ++r) sm.red[w][48 + quad*4 + r][col] = acc3[r];
    __syncthreads();

    const int jj = tid >> 2;               // 0..63
    const int eg = (tid & 3) * 4;          // 0,4,8,12
    float4 s4 = make_float4(0.f, 0.f, 0.f, 0.f);
    #pragma unroll
    for (int ww = 0; ww < 4; ++ww) {
        s4.x += sm.red[ww][jj][eg + 0];
        s4.y += sm.red[ww][jj][eg + 1];
        s4.z += sm.red[ww][jj][eg + 2];
        s4.w += sm.red[ww][jj][eg + 3];
    }
    float* og = out + XGRID_SIZE + (size_t)blockIdx.x * (W_ * DZ_);
    *(float4*)(og + jj*DZ_ + eg) = s4;
}

extern "C" void kernel_launch(void* const* d_in, const int* in_sizes, int n_in,
                              void* d_out, int out_size, void* d_ws, size_t ws_size,
                              hipStream_t stream) {
    const float* x   = (const float*)d_in[0];   // [B][N][3]
    const float* z   = (const float*)d_in[1];   // [B][N][16]
    const float* tg  = (const float*)d_in[2];   // [B][NT]
    const float* lsp = (const float*)d_in[3];   // [3]

    float* out = (float*)d_out;

    // ws layout: [16][N_] float4 lists (512 KB), then 16 ints of counts.
    float4* wsl  = (float4*)d_ws;
    int*    wcnt = (int*)((char*)d_ws + (size_t)16 * N_ * sizeof(float4));

    tcull_kernel<<<16, 1024, 0, stream>>>(x, tg, lsp, wsl, wcnt);
    fused_kernel<<<1024, 256, 0, stream>>>(z, tg, lsp, wsl, wcnt, out);
}

// Round 10
// 74.715 us; speedup vs baseline: 1.0109x; 1.0109x over previous
//
#include <hip/hip_runtime.h>
#include <math.h>

#define B_  2
#define N_  2048
#define NT_ 8
#define DZ_ 16
#define H_  64
#define W_  64

#define XGRID_SIZE (B_*NT_*H_*W_*3)   // 196608 floats
#define CUT 12.0f                     // per-axis cull bound
#define CH  128                       // K-chunk: 4 waves x K=32
#define NBUK 64                       // x1 sort buckets
#define SCAP 1024                     // kernel-B staged range capacity

using half8   = __attribute__((ext_vector_type(8))) _Float16;
using floatx4 = __attribute__((ext_vector_type(4))) float;

// ---------------------------------------------------------------------------
// R10: sorted t-lists -> the per-(b,t,i) candidate set is a CONTIGUOUS range.
//
// R9 lesson: shrinking the per-block ballot-compaction 2048->820 didn't pay;
// the compaction chain itself (load->ballot->LDS-atomic->scatter) is the
// cost. Eliminate it:
//   kernel A (16 blocks, one per (b,t)): cull dt^2 < CUT, bucket-sort
//     survivors by x1 (64-bucket LDS histogram + wave prefix-scan +
//     scatter). Writes packed float4 {x1*r1, x2*r2, dt^2, n} sorted, plus
//     the 65-entry bucket-offset table.
//   kernel B (1024 blocks): range = [off[lobuk], off[hibuk+1]) from the
//     offset table (gi +- sqrt(CUT)/r1, buckets rounded outward). Stage the
//     range into LDS with a coalesced float4 copy, folding di^2 into
//     s = fma(di,di,dt^2) at stage time -> exactly R8's {s,cx}+idx format.
//     K-loop/epilogue = R8's barrier-free k-split MFMA (validated).
// Boundary-bucket extras carry weight < 2^-12 and are simply summed:
// strictly MORE accurate than R8's joint cull (R8's set is a subset).
// ---------------------------------------------------------------------------

__global__ __launch_bounds__(1024) void sort_kernel(
    const float* __restrict__ x,      // [B][N][3]
    const float* __restrict__ tg,     // [B][NT]
    const float* __restrict__ lsp,    // [3]
    float4* __restrict__ wsl,         // [16][N_] sorted survivors
    int* __restrict__ woff)           // [16][NBUK+1] bucket offsets
{
    const int bt  = blockIdx.x;       // b*8 + t
    const int b   = bt >> 3;
    const int tid = threadIdx.x;

    const float C  = 0.84932180f;     // sqrt(0.5 * log2(e))
    const float r0 = C / (1e-5f + log1pf(expf(lsp[0])));
    const float r1 = C / (1e-5f + log1pf(expf(lsp[1])));
    const float r2 = C / (1e-5f + log1pf(expf(lsp[2])));

    const float tval = tg[bt];

    __shared__ int hist[NBUK];
    __shared__ int offs[NBUK + 1];
    __shared__ int cur[NBUK];

    if (tid < NBUK) hist[tid] = 0;
    __syncthreads();

    const float* __restrict__ xb = x + b*N_*3;

    // pass 1: cull + histogram (stash per-entry data in registers)
    float sx1[2], sx2[2], sdt2[2];
    int   sbuk[2], skey[2];
    bool  skeep[2];
    #pragma unroll
    for (int r = 0; r < 2; ++r) {
        int k = r*1024 + tid;
        float x0 = xb[k*3 + 0];
        float x1 = xb[k*3 + 1];
        float x2 = xb[k*3 + 2];
        float dt  = (tval - x0) * r0;
        float dt2 = dt * dt;
        bool keep = (dt2 < CUT);
        int buk = (int)((x1 + 1.0f) * (NBUK * 0.5f));
        buk = min(max(buk, 0), NBUK - 1);
        skeep[r] = keep; sbuk[r] = buk; skey[r] = k;
        sx1[r] = x1 * r1; sx2[r] = x2 * r2; sdt2[r] = dt2;
        if (keep) atomicAdd(&hist[buk], 1);
    }
    __syncthreads();

    // wave-0 inclusive scan over 64 buckets -> offsets + cursors
    if (tid < NBUK) {
        int h = hist[tid];
        int v = h;
        #pragma unroll
        for (int d = 1; d < NBUK; d <<= 1) {
            int u = __shfl_up(v, d, 64);
            if (tid >= d) v += u;
        }
        offs[tid + 1] = v;
        cur[tid] = v - h;              // exclusive start
        if (tid == 0) offs[0] = 0;
    }
    __syncthreads();

    // pass 2: scatter into sorted order (order within bucket arbitrary)
    float4* __restrict__ outl = wsl + (size_t)bt * N_;
    #pragma unroll
    for (int r = 0; r < 2; ++r) {
        if (skeep[r]) {
            int pos = atomicAdd(&cur[sbuk[r]], 1);
            outl[pos] = make_float4(sx1[r], sx2[r], sdt2[r],
                                    __int_as_float(skey[r]));
        }
    }
    __syncthreads();
    if (tid <= NBUK) woff[bt*(NBUK+1) + tid] = offs[tid];
}

__global__ __launch_bounds__(256, 4) void fused_kernel(
    const float* __restrict__ z,      // [B][N][16]
    const float* __restrict__ tg,     // [B][NT]
    const float* __restrict__ lsp,    // [3]
    const float4* __restrict__ wsl,   // [16][N_] sorted
    const int* __restrict__ woff,     // [16][NBUK+1]
    float* __restrict__ out)          // x_grid (196608) ++ z_grid (1048576)
{
    const int i    = blockIdx.x & 63;
    const int t    = (blockIdx.x >> 6) & 7;
    const int b    = blockIdx.x >> 9;
    const int bt   = b*NT_ + t;
    const int tid  = threadIdx.x;
    const int w    = tid >> 6;        // wave id = k-subrange
    const int lane = tid & 63;
    const int quad = lane >> 4;       // 0..3
    const int col  = lane & 15;       // A row (j in tile) / B col (e)

    const float step = 2.0f / 63.0f;
    const float C    = 0.84932180f;

    const float r1 = C / (1e-5f + log1pf(expf(lsp[1])));
    const float r2 = C / (1e-5f + log1pf(expf(lsp[2])));

    const float tval = tg[bt];
    const float gi   = -1.0f + step * (float)i;
    const float gir1 = gi * r1;

    // candidate range from the bucket-offset table (rounded outward)
    const float wid = sqrtf(CUT) / r1;
    int lob = (int)floorf((gi - wid + 1.0f) * (NBUK * 0.5f));
    int hib = (int)floorf((gi + wid + 1.0f) * (NBUK * 0.5f));
    lob = min(max(lob, 0), NBUK - 1);
    hib = min(max(hib, 0), NBUK - 1);
    const int lo = woff[bt*(NBUK+1) + lob];
    const int hi = woff[bt*(NBUK+1) + hib + 1];
    const int Mr = hi - lo;

    union SM {
        struct { float2 cuc[SCAP + CH]; int cidx[SCAP + CH]; } c;  // 13824 B
        float red[4][64][DZ_ + 1];                                 // 17408 B
    };
    __shared__ SM sm;

    // x_grid row for this (b,t,i): 192 floats, coalesced
    if (tid < 192) {
        int jj = tid / 3;
        int c  = tid - jj*3;
        float gj = -1.0f + step * (float)jj;
        float v  = (c == 0) ? tval : ((c == 1) ? gi : gj);
        out[(size_t)blockIdx.x * 192 + tid] = v;
    }

    const float* __restrict__ zb  = z + b*N_*DZ_;
    const float4* __restrict__ lst = wsl + (size_t)bt * N_;
    const int koff = w*32 + (quad << 3);   // lane's k-base within a chunk

    const float aj0 = (-1.0f + step * (float)( 0 + col)) * r2;
    const float aj1 = (-1.0f + step * (float)(16 + col)) * r2;
    const float aj2 = (-1.0f + step * (float)(32 + col)) * r2;
    const float aj3 = (-1.0f + step * (float)(48 + col)) * r2;

    floatx4 acc0 = {0.f,0.f,0.f,0.f};
    floatx4 acc1 = {0.f,0.f,0.f,0.f};
    floatx4 acc2 = {0.f,0.f,0.f,0.f};
    floatx4 acc3 = {0.f,0.f,0.f,0.f};

    int nst = (Mr + SCAP - 1) / SCAP;
    if (nst < 1) nst = 1;

    for (int st = 0; st < nst; ++st) {
        const int sbase = lo + st * SCAP;
        int cnt = hi - sbase;
        cnt = min(cnt, SCAP);
        cnt = max(cnt, 0);

        if (st > 0) __syncthreads();       // prev stage fully consumed

        // stage: coalesced copy + fold di^2 into s at stage time
        for (int k = tid; k < cnt; k += 256) {
            float4 f = lst[sbase + k];
            float di = gir1 - f.x;
            sm.c.cuc[k]  = make_float2(fmaf(di, di, f.z), f.y);
            sm.c.cidx[k] = __float_as_int(f.w);
        }
        const int cpad = (cnt + CH - 1) & ~(CH - 1);
        for (int k = cnt + tid; k < cpad; k += 256) {
            sm.c.cuc[k]  = make_float2(1e9f, 0.f);   // weight -> 0
            sm.c.cidx[k] = 0;
        }
        __syncthreads();

        const int NC = cpad >> 7;          // 128-entry chunks this stage

        // ---- R8's barrier-free k-split MFMA K-loop ----
        float zreg[8];
        if (NC > 0) {
            int idx[8];
            #pragma unroll
            for (int jj = 0; jj < 8; ++jj) idx[jj] = sm.c.cidx[koff + jj];
            #pragma unroll
            for (int jj = 0; jj < 8; ++jj)
                zreg[jj] = zb[(size_t)idx[jj] * DZ_ + col];
        }

        for (int c = 0; c < NC; ++c) {
            half8 bf;
            #pragma unroll
            for (int jj = 0; jj < 8; ++jj) bf[jj] = (_Float16)zreg[jj];

            const int base = c*CH + koff;
            float2 mm[8];
            #pragma unroll
            for (int jj = 0; jj < 8; ++jj) mm[jj] = sm.c.cuc[base + jj];

            if (c + 1 < NC) {
                const int base2 = (c + 1)*CH + koff;
                int idx[8];
                #pragma unroll
                for (int jj = 0; jj < 8; ++jj) idx[jj] = sm.c.cidx[base2 + jj];
                #pragma unroll
                for (int jj = 0; jj < 8; ++jj)
                    zreg[jj] = zb[(size_t)idx[jj] * DZ_ + col];
            }

            half8 a0, a1, a2, a3;
            #pragma unroll
            for (int jj = 0; jj < 8; ++jj) {
                float s  = mm[jj].x;
                float cx = mm[jj].y;
                float d0 = aj0 - cx;
                float d1 = aj1 - cx;
                float d2 = aj2 - cx;
                float d3 = aj3 - cx;
                a0[jj] = (_Float16)exp2f(-fmaf(d0, d0, s));
                a1[jj] = (_Float16)exp2f(-fmaf(d1, d1, s));
                a2[jj] = (_Float16)exp2f(-fmaf(d2, d2, s));
                a3[jj] = (_Float16)exp2f(-fmaf(d3, d3, s));
            }

            acc0 = __builtin_amdgcn_mfma_f32_16x16x32_f16(a0, bf, acc0, 0, 0, 0);
            acc1 = __builtin_amdgcn_mfma_f32_16x16x32_f16(a1, bf, acc1, 0, 0, 0);
            acc2 = __builtin_amdgcn_mfma_f32_16x16x32_f16(a2, bf, acc2, 0, 0, 0);
            acc3 = __builtin_amdgcn_mfma_f32_16x16x32_f16(a3, bf, acc3, 0, 0, 0);
        }
    }

    __syncthreads();   // all cuc reads done before red overlays it

    // ---- epilogue: reduce 4 k-partials across waves, store z_grid ----
    #pragma unroll
    for (int r = 0; r < 4; ++r) sm.red[w][ 0 + quad*4 + r][col] = acc0[r];
    #pragma unroll
    for (int r = 0; r < 4; ++r) sm.red[w][16 + quad*4 + r][col] = acc1[r];
    #pragma unroll
    for (int r = 0; r < 4; ++r) sm.red[w][32 + quad*4 + r][col] = acc2[r];
    #pragma unroll
    for (int r = 0; r < 4; ++r) sm.red[w][48 + quad*4 + r][col] = acc3[r];
    __syncthreads();

    const int jj = tid >> 2;               // 0..63
    const int eg = (tid & 3) * 4;          // 0,4,8,12
    float4 s4 = make_float4(0.f, 0.f, 0.f, 0.f);
    #pragma unroll
    for (int ww = 0; ww < 4; ++ww) {
        s4.x += sm.red[ww][jj][eg + 0];
        s4.y += sm.red[ww][jj][eg + 1];
        s4.z += sm.red[ww][jj][eg + 2];
        s4.w += sm.red[ww][jj][eg + 3];
    }
    float* og = out + XGRID_SIZE + (size_t)blockIdx.x * (W_ * DZ_);
    *(float4*)(og + jj*DZ_ + eg) = s4;
}

extern "C" void kernel_launch(void* const* d_in, const int* in_sizes, int n_in,
                              void* d_out, int out_size, void* d_ws, size_t ws_size,
                              hipStream_t stream) {
    const float* x   = (const float*)d_in[0];   // [B][N][3]
    const float* z   = (const float*)d_in[1];   // [B][N][16]
    const float* tg  = (const float*)d_in[2];   // [B][NT]
    const float* lsp = (const float*)d_in[3];   // [3]

    float* out = (float*)d_out;

    // ws layout: [16][N_] float4 sorted lists (512 KB), then [16][65] ints.
    float4* wsl  = (float4*)d_ws;
    int*    woff = (int*)((char*)d_ws + (size_t)16 * N_ * sizeof(float4));

    sort_kernel<<<16, 1024, 0, stream>>>(x, tg, lsp, wsl, woff);
    fused_kernel<<<1024, 256, 0, stream>>>(z, tg, lsp, wsl, woff, out);
}

// Round 11
// 72.336 us; speedup vs baseline: 1.0441x; 1.0329x over previous
//
#include <hip/hip_runtime.h>
#include <math.h>

#define B_  2
#define N_  2048
#define NT_ 8
#define DZ_ 16
#define H_  64
#define W_  64

#define XGRID_SIZE (B_*NT_*H_*W_*3)   // 196608 floats
#define CUT 12.0f                     // keep if dt^2+di^2 < 12 (w > 2.4e-4)
#define CH  128                       // K-chunk: 4 waves x K=32

using half8   = __attribute__((ext_vector_type(8))) _Float16;
using floatx4 = __attribute__((ext_vector_type(4))) float;

// ---------------------------------------------------------------------------
// R11 = R8 (best measured: 72.8 us) + batched phase-1 loads.
//
// R9 (pre-culled lists) and R10 (bucket-sorted ranges) both reverted: they
// eliminated per-block cull work but added a launch + sort that ate the
// gain (bench 75.5 / 74.7 vs R8's 72.8 — the compute NC was unchanged).
//
// Phase-1 fix vs R8: all 24 x-floats (8 entries/thread) are loaded up-front
// in one vmcnt window; the 8 ballot->LDS-atomic->scatter steps then execute
// with no memory latency inside the chain (R8 serialized 8 x ~450 cy
// load-chains).
//
// Phase 2 (unchanged, validated): wave w owns k-subrange [w*32,w*32+32) of
// each 128-entry chunk, computes all four 16x16 j-tiles from one B-frag
// loaded directly from global z (64 B coalesced per quad, L2-resident),
// 1-chunk-deep prefetch, NO barriers in the K-loop.
// MFMA f16 16x16x32: A[m=lane&15][k=quad*8+jj], B[k][n=lane&15],
// D: col=lane&15, row=quad*4+reg.
// Epilogue: stride-17 LDS reduce of 4 k-partials, coalesced float4 stores.
// No atomics, no memset, no workspace.
// ---------------------------------------------------------------------------
__global__ __launch_bounds__(256, 4) void fused_kernel(
    const float* __restrict__ x,      // [B][N][3]
    const float* __restrict__ z,      // [B][N][16]
    const float* __restrict__ tg,     // [B][NT]
    const float* __restrict__ lsp,    // [3]
    float* __restrict__ out)          // x_grid (196608) ++ z_grid (1048576)
{
    const int i    = blockIdx.x & 63;
    const int t    = (blockIdx.x >> 6) & 7;
    const int b    = blockIdx.x >> 9;
    const int tid  = threadIdx.x;
    const int w    = tid >> 6;        // wave id = k-subrange
    const int lane = tid & 63;
    const int quad = lane >> 4;       // 0..3
    const int col  = lane & 15;       // A row (j in tile) / B col (e)

    const float step = 2.0f / 63.0f;
    const float C    = 0.84932180f;   // sqrt(0.5 * log2(e))

    const float r0 = C / (1e-5f + log1pf(expf(lsp[0])));
    const float r1 = C / (1e-5f + log1pf(expf(lsp[1])));
    const float r2 = C / (1e-5f + log1pf(expf(lsp[2])));

    const float tval = tg[b*NT_ + t];
    const float gi   = -1.0f + step * (float)i;

    union REDU {
        float2 cuc[N_ + CH];           // {s, cx}: 17408 B (phases 1-2)
        float  red[4][64][DZ_ + 1];    // 17408 B (epilogue reduce)
    };
    __shared__ REDU sm;
    __shared__ int  cidx[N_ + CH];     // 8704 B
    __shared__ int  s_cnt;

    if (tid == 0) s_cnt = 0;
    __syncthreads();

    // ---- phase 1: cull + compact (s = dt^2+di^2, cx) over all n ----
    // All 8 entries' x-triples loaded first (one vmcnt window), then the 8
    // ballot/scatter chains run with no memory stalls inside them.
    const float* __restrict__ xb = x + b*N_*3;
    {
        float px0[8], px1[8], px2[8];
        #pragma unroll
        for (int r = 0; r < 8; ++r) {
            int k = r*256 + tid;
            px0[r] = xb[k*3 + 0];
            px1[r] = xb[k*3 + 1];
            px2[r] = xb[k*3 + 2];
        }
        #pragma unroll
        for (int r = 0; r < 8; ++r) {
            int k = r*256 + tid;
            float dt = (tval - px0[r]) * r0;
            float di = (gi   - px1[r]) * r1;
            float sq = fmaf(dt, dt, di*di);
            bool keep = (sq < CUT);
            unsigned long long mb = __ballot(keep);
            int cnt = __popcll(mb);
            int base = 0;
            if (lane == 0) base = atomicAdd(&s_cnt, cnt);
            base = __shfl(base, 0, 64);
            if (keep) {
                int rank = __popcll(mb & ((1ull << lane) - 1ull));
                int pos  = base + rank;
                sm.cuc[pos] = make_float2(sq, px2[r] * r2);
                cidx[pos]   = k;
            }
        }
    }

    // x_grid row for this (b,t,i): 192 floats, coalesced
    if (tid < 192) {
        int jj = tid / 3;
        int c  = tid - jj*3;
        float gj = -1.0f + step * (float)jj;
        float v  = (c == 0) ? tval : ((c == 1) ? gi : gj);
        out[(size_t)blockIdx.x * 192 + tid] = v;
    }

    __syncthreads();
    const int M = s_cnt;
    if (tid < CH) {                    // pad: s huge -> exp2(-(d^2+s)) == 0
        sm.cuc[M + tid] = make_float2(1e9f, 0.f);
        cidx[M + tid]   = 0;
    }
    __syncthreads();

    const int NC = (M + CH - 1) / CH;  // 128-entry chunks

    // ---- phase 2: barrier-free MFMA K-loop ----
    const float* __restrict__ zb = z + b*N_*DZ_;
    const int koff = w*32 + (quad << 3);   // this lane's k-base within a chunk

    const float aj0 = (-1.0f + step * (float)( 0 + col)) * r2;
    const float aj1 = (-1.0f + step * (float)(16 + col)) * r2;
    const float aj2 = (-1.0f + step * (float)(32 + col)) * r2;
    const float aj3 = (-1.0f + step * (float)(48 + col)) * r2;

    floatx4 acc0 = {0.f,0.f,0.f,0.f};
    floatx4 acc1 = {0.f,0.f,0.f,0.f};
    floatx4 acc2 = {0.f,0.f,0.f,0.f};
    floatx4 acc3 = {0.f,0.f,0.f,0.f};

    // prologue: B dwords for chunk 0 (pads make indices always valid)
    float zreg[8];
    {
        int idx[8];
        #pragma unroll
        for (int jj = 0; jj < 8; ++jj) idx[jj] = cidx[koff + jj];
        #pragma unroll
        for (int jj = 0; jj < 8; ++jj)
            zreg[jj] = zb[(size_t)idx[jj] * DZ_ + col];
    }

    for (int c = 0; c < NC; ++c) {
        // pack current B fragment
        half8 bf;
        #pragma unroll
        for (int jj = 0; jj < 8; ++jj) bf[jj] = (_Float16)zreg[jj];

        // meta for current chunk (quad-uniform broadcast, 8 entries/lane)
        const int base = c*CH + koff;
        float2 mm[8];
        #pragma unroll
        for (int jj = 0; jj < 8; ++jj) mm[jj] = sm.cuc[base + jj];

        // prefetch next chunk's B dwords (land during exp/MFMA below)
        if (c + 1 < NC) {
            const int base2 = (c + 1)*CH + koff;
            int idx[8];
            #pragma unroll
            for (int jj = 0; jj < 8; ++jj) idx[jj] = cidx[base2 + jj];
            #pragma unroll
            for (int jj = 0; jj < 8; ++jj)
                zreg[jj] = zb[(size_t)idx[jj] * DZ_ + col];
        }

        // A fragments for the 4 j-tiles
        half8 a0, a1, a2, a3;
        #pragma unroll
        for (int jj = 0; jj < 8; ++jj) {
            float s  = mm[jj].x;
            float cx = mm[jj].y;
            float d0 = aj0 - cx;
            float d1 = aj1 - cx;
            float d2 = aj2 - cx;
            float d3 = aj3 - cx;
            a0[jj] = (_Float16)exp2f(-fmaf(d0, d0, s));
            a1[jj] = (_Float16)exp2f(-fmaf(d1, d1, s));
            a2[jj] = (_Float16)exp2f(-fmaf(d2, d2, s));
            a3[jj] = (_Float16)exp2f(-fmaf(d3, d3, s));
        }

        acc0 = __builtin_amdgcn_mfma_f32_16x16x32_f16(a0, bf, acc0, 0, 0, 0);
        acc1 = __builtin_amdgcn_mfma_f32_16x16x32_f16(a1, bf, acc1, 0, 0, 0);
        acc2 = __builtin_amdgcn_mfma_f32_16x16x32_f16(a2, bf, acc2, 0, 0, 0);
        acc3 = __builtin_amdgcn_mfma_f32_16x16x32_f16(a3, bf, acc3, 0, 0, 0);
    }

    __syncthreads();   // all cuc reads done before red overlays it

    // ---- epilogue: reduce 4 k-partials across waves, store z_grid ----
    // D layout: row = quad*4 + reg, col = lane&15.
    #pragma unroll
    for (int r = 0; r < 4; ++r) sm.red[w][ 0 + quad*4 + r][col] = acc0[r];
    #pragma unroll
    for (int r = 0; r < 4; ++r) sm.red[w][16 + quad*4 + r][col] = acc1[r];
    #pragma unroll
    for (int r = 0; r < 4; ++r) sm.red[w][32 + quad*4 + r][col] = acc2[r];
    #pragma unroll
    for (int r = 0; r < 4; ++r) sm.red[w][48 + quad*4 + r][col] = acc3[r];
    __syncthreads();

    const int jj = tid >> 2;               // 0..63
    const int eg = (tid & 3) * 4;          // 0,4,8,12
    float4 s4 = make_float4(0.f, 0.f, 0.f, 0.f);
    #pragma unroll
    for (int ww = 0; ww < 4; ++ww) {
        s4.x += sm.red[ww][jj][eg + 0];
        s4.y += sm.red[ww][jj][eg + 1];
        s4.z += sm.red[ww][jj][eg + 2];
        s4.w += sm.red[ww][jj][eg + 3];
    }
    float* og = out + XGRID_SIZE + (size_t)blockIdx.x * (W_ * DZ_);
    *(float4*)(og + jj*DZ_ + eg) = s4;
}

extern "C" void kernel_launch(void* const* d_in, const int* in_sizes, int n_in,
                              void* d_out, int out_size, void* d_ws, size_t ws_size,
                              hipStream_t stream) {
    const float* x   = (const float*)d_in[0];   // [B][N][3]
    const float* z   = (const float*)d_in[1];   // [B][N][16]
    const float* tg  = (const float*)d_in[2];   // [B][NT]
    const float* lsp = (const float*)d_in[3];   // [3]

    float* out = (float*)d_out;

    // 1024 blocks, one per (b,t,i) row; no workspace, no memset, no atomics.
    fused_kernel<<<1024, 256, 0, stream>>>(x, z, tg, lsp, out);
}